// Round 12
// baseline (36.487 us; speedup 1.0000x reference)
//
#include <hip/hip_runtime.h>
#include <hip/hip_bf16.h>

#define NPE   512
#define F_IN  128
#define HDIM  16
#define ODIM  10
#define B_EV  512
#define NTOT  (B_EV * NPE)
#define KNNBLK 512
#define STRBLK 2048

typedef __attribute__((ext_vector_type(8))) short short8;
typedef __attribute__((ext_vector_type(4))) float f32x4;

static __device__ __forceinline__ unsigned pkbf(float lo, float hi) {
  __hip_bfloat162 h = __float22bfloat162_rn(make_float2(lo, hi));
  unsigned r;
  __builtin_memcpy(&r, &h, 4);                     // v_cvt_pk_bf16_f32
  return r;
}
static __device__ __forceinline__ short f2bf(float f) {
  __hip_bfloat16 h = __float2bfloat16(f);
  short r;
  __builtin_memcpy(&r, &h, 2);
  return r;
}
static __device__ __forceinline__ float bflo(unsigned d) {
  return __builtin_bit_cast(float, d << 16);
}
static __device__ __forceinline__ float bfhi(unsigned d) {
  return __builtin_bit_cast(float, d & 0xffff0000u);
}
static __device__ __forceinline__ unsigned umin2(unsigned a, unsigned b) { return a < b ? a : b; }
static __device__ __forceinline__ unsigned umax2(unsigned a, unsigned b) { return a > b ? a : b; }

// ================= Kernel A: knn blocks (0..511) + streaming GEMM1 blocks =====
__global__ __launch_bounds__(256, 6) void gnet_a(
    const int* __restrict__ coo, const float* __restrict__ x,
    const float* __restrict__ W1,
    unsigned short* __restrict__ h1g,      // [NTOT][16] bf16
    uint4* __restrict__ nbg)               // [NTOT] packed 6 x ushort
{
  __shared__ __align__(16) short slab_s[4][2048];  // 16 KB: 4 waves x (16x128 bf16)
  __shared__ unsigned short cellof_s[NPE];
  __shared__ unsigned cnt_s[256], scan_s[256], cur_s[256], wtot_s[4];
  __shared__ unsigned short bucket_s[NPE];

  const int tid = threadIdx.x;
  const int ln  = tid & 63;
  const int wv  = tid >> 6;

  if (blockIdx.x < KNNBLK) {
    // ---------------- knn block: one event, 256 threads ----------------
    const int gbase = blockIdx.x * NPE;
#pragma unroll
    for (int q = 0; q < 2; ++q) {
      const int node = tid + q * 256;
      const int cx = coo[(gbase + node) * 3 + 0];
      const int cy = coo[(gbase + node) * 3 + 1];
      cellof_s[node] = (unsigned short)(cy * 16 + cx);
    }
    cnt_s[tid] = 0;
    __syncthreads();
    atomicAdd(&cnt_s[cellof_s[tid]], 1u);
    atomicAdd(&cnt_s[cellof_s[tid + 256]], 1u);
    __syncthreads();
    unsigned sv = cnt_s[tid];
#pragma unroll
    for (int off = 1; off < 64; off <<= 1) {
      unsigned u = __shfl_up(sv, off, 64);
      if (ln >= off) sv += u;
    }
    if (ln == 63) wtot_s[wv] = sv;
    __syncthreads();
    unsigned add = 0;
#pragma unroll
    for (int w = 0; w < 3; ++w) if (w < wv) add += wtot_s[w];
    sv += add;
    scan_s[tid] = sv;                 // inclusive
    cur_s[tid]  = sv - cnt_s[tid];    // exclusive start
    __syncthreads();
#pragma unroll
    for (int q = 0; q < 2; ++q) {
      const int node = tid + q * 256;
      const unsigned slot = atomicAdd(&cur_s[cellof_s[node]], 1u);
      bucket_s[slot] = (unsigned short)node;
    }
    __syncthreads();

    const unsigned n = cnt_s[tid];
    if (n) {
      const int ccx = tid & 15, ccy = tid >> 4;
      unsigned k0 = 0x7fffffffu, k1 = k0, k2 = k0, k3 = k0, k4 = k0, k5 = k0, k6 = k0;
      auto insert7 = [&](unsigned key) {
        if (key < k6) {
          k6 = key;
          unsigned lo, hi;
          lo = umin2(k5, k6); hi = umax2(k5, k6); k5 = lo; k6 = hi;
          lo = umin2(k4, k5); hi = umax2(k4, k5); k4 = lo; k5 = hi;
          lo = umin2(k3, k4); hi = umax2(k3, k4); k3 = lo; k4 = hi;
          lo = umin2(k2, k3); hi = umax2(k2, k3); k2 = lo; k3 = hi;
          lo = umin2(k1, k2); hi = umax2(k1, k2); k1 = lo; k2 = hi;
          lo = umin2(k0, k1); hi = umax2(k0, k1); k0 = lo; k1 = hi;
        }
      };
      auto scan_cell = [&](int c, unsigned kb) {
        const unsigned e = scan_s[c];
        const unsigned m = cnt_s[c];
        for (unsigned q = e - m; q < e; ++q) insert7(kb | (unsigned)bucket_s[q]);
      };
      scan_cell(tid, 0u);
      for (int r = 1; r <= 15; ++r) {
        const unsigned r2 = (unsigned)(r * r);
        if (r2 > (k6 >> 9)) break;
        for (int sg = 0; sg < 2; ++sg) {            // rows dy = ±r
          const int yy = ccy + (sg ? r : -r);
          if (yy < 0 || yy > 15) continue;
          const int xlo = ccx - r < 0 ? 0 : ccx - r;
          const int xhi = ccx + r > 15 ? 15 : ccx + r;
          for (int xx = xlo; xx <= xhi; ++xx) {
            const int dx = xx - ccx;
            const unsigned kb = (unsigned)(dx * dx + (int)r2) << 9;
            if (kb < k6) scan_cell(yy * 16 + xx, kb);
          }
        }
        for (int sg = 0; sg < 2; ++sg) {            // cols dx = ±r
          const int xx = ccx + (sg ? r : -r);
          if (xx < 0 || xx > 15) continue;
          const int ylo = ccy - r + 1 < 0 ? 0 : ccy - r + 1;
          const int yhi = ccy + r - 1 > 15 ? 15 : ccy + r - 1;
          for (int yy = ylo; yy <= yhi; ++yy) {
            const int dy = yy - ccy;
            const unsigned kb = (unsigned)(dy * dy + (int)r2) << 9;
            if (kb < k6) scan_cell(yy * 16 + xx, kb);
          }
        }
      }
      // emit per-member neighbor list (self key = node id, d2=0)
      const unsigned eend = scan_s[tid];
      for (unsigned q = eend - n; q < eend; ++q) {
        const unsigned node = bucket_s[q];
        int p = 7;
        p = (k6 == node) ? 6 : p;
        p = (k5 == node) ? 5 : p;
        p = (k4 == node) ? 4 : p;
        p = (k3 == node) ? 3 : p;
        p = (k2 == node) ? 2 : p;
        p = (k1 == node) ? 1 : p;
        p = (k0 == node) ? 0 : p;
        const unsigned n0 = (p > 0 ? k0 : k1) & 511u;
        const unsigned n1 = (p > 1 ? k1 : k2) & 511u;
        const unsigned n2 = (p > 2 ? k2 : k3) & 511u;
        const unsigned n3 = (p > 3 ? k3 : k4) & 511u;
        const unsigned n4 = (p > 4 ? k4 : k5) & 511u;
        const unsigned n5 = (p > 5 ? k5 : k6) & 511u;
        uint4 pk;
        pk.x = n0 | (n1 << 16);
        pk.y = n2 | (n3 << 16);
        pk.z = n4 | (n5 << 16);
        pk.w = 0u;
        nbg[gbase + node] = pk;
      }
    }
  } else {
    // ---------------- streaming GEMM1 block: 128 rows, 4 waves x 2 tiles ------
    const int sb   = blockIdx.x - KNNBLK;
    const int lcol = ln & 15;
    const int lkg  = ln >> 4;
    short8 bw1[4];
#pragma unroll
    for (int s = 0; s < 4; ++s) {
#pragma unroll
      for (int e = 0; e < 8; ++e) {
        const int k = s * 32 + lkg * 8 + e;
        bw1[s][e] = f2bf(W1[k * HDIM + lcol]);
      }
    }
    short* slab = &slab_s[wv][0];
    const int srow = ln >> 5;          // 0..1
    const int scol = (ln & 31) * 4;    // 0..124 (floats)
    const int gw = sb * 128 + wv * 32; // wave's 32 rows

#pragma unroll
    for (int half = 0; half < 2; ++half) {
      const int gr = gw + half * 16;
      const float* xrow = x + (size_t)(gr + srow) * F_IN + scol;
      float4 v[4];
#pragma unroll
      for (int j = 0; j < 4; ++j)
        v[j] = *reinterpret_cast<const float4*>(xrow + (size_t)(2 * j) * F_IN);
#pragma unroll
      for (int j = 0; j < 4; ++j)
        *reinterpret_cast<uint2*>(&slab[(2 * j + srow) * 128 + scol]) =
            make_uint2(pkbf(v[j].x, v[j].y), pkbf(v[j].z, v[j].w));
#pragma unroll
      for (int j = 0; j < 4; ++j)
        v[j] = *reinterpret_cast<const float4*>(xrow + (size_t)(2 * j + 8) * F_IN);
#pragma unroll
      for (int j = 0; j < 4; ++j)
        *reinterpret_cast<uint2*>(&slab[(2 * j + 8 + srow) * 128 + scol]) =
            make_uint2(pkbf(v[j].x, v[j].y), pkbf(v[j].z, v[j].w));

      f32x4 acc = {0.f, 0.f, 0.f, 0.f};
#pragma unroll
      for (int s = 0; s < 4; ++s) {
        const short8 af = *reinterpret_cast<const short8*>(
            &slab[lcol * 128 + s * 32 + lkg * 8]);
        acc = __builtin_amdgcn_mfma_f32_16x16x32_bf16(af, bw1[s], acc, 0, 0, 0);
      }
      // stage C-tile (16x16 bf16 = 512 B) into slab head, then coalesced store
#pragma unroll
      for (int i = 0; i < 4; ++i)
        slab[(lkg * 4 + i) * 16 + lcol] = f2bf(acc[i]);  // col=lane&15,row=(lane>>4)*4+i
      asm volatile("s_waitcnt lgkmcnt(0)" ::: "memory");
      const uint2 d = *reinterpret_cast<const uint2*>(&slab[ln * 4]);
      *reinterpret_cast<uint2*>(h1g + (size_t)gr * 16 + ln * 4) = d;
    }
  }
}

// ================= Kernel B: gather + agg1(ReLU) + agg2 + GEMM2 ==============
__global__ __launch_bounds__(512, 4) void gnet_b(
    const unsigned short* __restrict__ h1g, const uint4* __restrict__ nbg,
    const float* __restrict__ b1, const float* __restrict__ W2,
    const float* __restrict__ b2, float* __restrict__ out)
{
  __shared__ __align__(16) short h1_s[NPE][16];   // 16 KB
  __shared__ __align__(16) short r_s [NPE][16];   // 16 KB
  __shared__ __align__(16) short agg_s[NPE][16];  // 16 KB

  const int tid   = threadIdx.x;
  const int ln    = tid & 63;
  const int wv    = tid >> 6;
  const int lcol  = ln & 15;
  const int lkg   = ln >> 4;
  const int gbase = blockIdx.x * NPE;

  {
    const uint4* src = reinterpret_cast<const uint4*>(h1g + (size_t)gbase * 16);
    const uint4 a = src[tid * 2];
    const uint4 b = src[tid * 2 + 1];
    uint4* dst = reinterpret_cast<uint4*>(&h1_s[tid][0]);
    dst[0] = a; dst[1] = b;
  }
  const uint4 nb = nbg[gbase + tid];
  const int rows[7] = {tid,
                       (int)(nb.x & 0xffffu), (int)(nb.x >> 16),
                       (int)(nb.y & 0xffffu), (int)(nb.y >> 16),
                       (int)(nb.z & 0xffffu), (int)(nb.z >> 16)};
  __syncthreads();

  // Phase C: r = relu((self + 6 nbrs)/7 + b1) -> r_s (bf16)
  {
    float acc[HDIM];
#pragma unroll
    for (int o = 0; o < HDIM; ++o) acc[o] = 0.f;
#pragma unroll
    for (int r = 0; r < 7; ++r) {
      const uint4* hp = reinterpret_cast<const uint4*>(&h1_s[rows[r]][0]);
      const uint4 ha = hp[0];
      const uint4 hb = hp[1];
      const unsigned hd[8] = {ha.x, ha.y, ha.z, ha.w, hb.x, hb.y, hb.z, hb.w};
#pragma unroll
      for (int q = 0; q < 8; ++q) {
        acc[2 * q]     += bflo(hd[q]);
        acc[2 * q + 1] += bfhi(hd[q]);
      }
    }
    const float inv = 1.0f / 7.0f;
    unsigned pk[8];
#pragma unroll
    for (int q = 0; q < 8; ++q) {
      const float v0 = fmaxf(acc[2 * q]     * inv + b1[2 * q],     0.f);
      const float v1 = fmaxf(acc[2 * q + 1] * inv + b1[2 * q + 1], 0.f);
      pk[q] = pkbf(v0, v1);
    }
    uint4* rp = reinterpret_cast<uint4*>(&r_s[tid][0]);
    rp[0] = make_uint4(pk[0], pk[1], pk[2], pk[3]);
    rp[1] = make_uint4(pk[4], pk[5], pk[6], pk[7]);
  }
  __syncthreads();

  // Phase C2: agg_r = (self + 6 nbrs r)/7 -> agg_s  (linearity with W2)
  {
    float acc[HDIM];
#pragma unroll
    for (int o = 0; o < HDIM; ++o) acc[o] = 0.f;
#pragma unroll
    for (int r = 0; r < 7; ++r) {
      const uint4* hp = reinterpret_cast<const uint4*>(&r_s[rows[r]][0]);
      const uint4 ha = hp[0];
      const uint4 hb = hp[1];
      const unsigned hd[8] = {ha.x, ha.y, ha.z, ha.w, hb.x, hb.y, hb.z, hb.w};
#pragma unroll
      for (int q = 0; q < 8; ++q) {
        acc[2 * q]     += bflo(hd[q]);
        acc[2 * q + 1] += bfhi(hd[q]);
      }
    }
    const float inv = 1.0f / 7.0f;
    unsigned pk[8];
#pragma unroll
    for (int q = 0; q < 8; ++q) {
      pk[q] = pkbf(acc[2 * q] * inv, acc[2 * q + 1] * inv);
    }
    uint4* ap = reinterpret_cast<uint4*>(&agg_s[tid][0]);
    ap[0] = make_uint4(pk[0], pk[1], pk[2], pk[3]);
    ap[1] = make_uint4(pk[4], pk[5], pk[6], pk[7]);
  }
  __syncthreads();

  // Phase D: out = agg_r @ W2 + b2 (MFMA, K=16 padded to 32)
  {
    short8 bw2 = {0, 0, 0, 0, 0, 0, 0, 0};
    if (lkg < 2 && lcol < ODIM) {
#pragma unroll
      for (int e = 0; e < 8; ++e) {
        const int k = lkg * 8 + e;
        bw2[e] = f2bf(W2[k * ODIM + lcol]);
      }
    }
    const float b2v = (lcol < ODIM) ? b2[lcol] : 0.f;
#pragma unroll
    for (int t = 0; t < 4; ++t) {
      const int nt = wv * 64 + t * 16;
      short8 af = {0, 0, 0, 0, 0, 0, 0, 0};
      if (lkg < 2) {
        af = *reinterpret_cast<const short8*>(&agg_s[nt + lcol][lkg * 8]);
      }
      f32x4 acc = {0.f, 0.f, 0.f, 0.f};
      acc = __builtin_amdgcn_mfma_f32_16x16x32_bf16(af, bw2, acc, 0, 0, 0);
      if (lcol < ODIM) {
#pragma unroll
        for (int i = 0; i < 4; ++i) {
          __builtin_nontemporal_store(
              acc[i] + b2v,
              out + (size_t)(gbase + nt + lkg * 4 + i) * ODIM + lcol);
        }
      }
    }
  }
}

extern "C" void kernel_launch(void* const* d_in, const int* in_sizes, int n_in,
                              void* d_out, int out_size, void* d_ws, size_t ws_size,
                              hipStream_t stream) {
  const int*   coo = (const int*)  d_in[0];
  const float* x   = (const float*)d_in[1];
  const float* W1  = (const float*)d_in[2];
  const float* b1  = (const float*)d_in[3];
  const float* W2  = (const float*)d_in[4];
  const float* b2  = (const float*)d_in[5];

  unsigned short* h1g = (unsigned short*)d_ws;                       // 8 MB
  uint4*          nbg = (uint4*)((char*)d_ws + (size_t)NTOT * 16 * 2); // +4 MB

  gnet_a<<<dim3(KNNBLK + STRBLK), dim3(256), 0, stream>>>(coo, x, W1, h1g, nbg);
  gnet_b<<<dim3(B_EV), dim3(512), 0, stream>>>(h1g, nbg, b1, W2, b2, (float*)d_out);
}